// Round 18
// baseline (61.695 us; speedup 1.0000x reference)
//
#include <hip/hip_runtime.h>
#include <hip/hip_fp16.h>

#define NB 4
#define CI 64
#define CO 128
#define HH 128
#define WW 128
#define HWSZ (HH*WW)
#define TOTPX (NB*HWSZ)     // 65536
#define NN 9

using half8 = __attribute__((ext_vector_type(8))) _Float16;
using f32x4 = __attribute__((ext_vector_type(4))) float;
using f32x2 = __attribute__((ext_vector_type(2))) float;

// ---- K0: prep W (fragment-major f16) + offset-conv weights (tap-major) ----
__global__ __launch_bounds__(256) void k_prep_w(const float* __restrict__ w,
                                                unsigned short* __restrict__ waF,
                                                const float* __restrict__ w_off,
                                                float* __restrict__ wP) {
    int t = blockIdx.x * 256 + threadIdx.x;
    if (t < CO * 576) {
        int oc = t / 576, r = t - oc * 576;
        int c = r / 9, n = r - c * 9;
        int i = oc >> 4, col = oc & 15;
        int ks = c >> 5, koct = (c >> 3) & 3, e = c & 7;
        int lane = koct * 16 + col;
        waF[(n * 16 + i * 2 + ks) * 512 + lane * 8 + e] =
            __half_as_ushort(__float2half_rn(w[t]));
    }
    if (t < 18 * 576) {
        int oc = t / 576, r = t - oc * 576;
        wP[r * 20 + oc] = w_off[t];
    }
}

// -- K1: offset conv (r12-v2 verbatim): 512 thr / 8ch-per-wave, 32 waves/CU --
__global__ __launch_bounds__(512, 8) void k_offsets(
    const float* __restrict__ x, const float* __restrict__ wP,
    const float* __restrict__ b_off, uchar4* __restrict__ dC,
    ushort4* __restrict__ dG, unsigned short* __restrict__ xT)
{
    __shared__ f32x2 sm[512 * 9];    // per-thread partials [tid][j]
    int bid = blockIdx.x;
    int b = bid >> 8, rem = bid & 255, y = rem >> 1, x0 = (rem & 1) << 6;
    int t = threadIdx.x;
    int pxl = t & 63;
    int g   = __builtin_amdgcn_readfirstlane(t >> 6);   // wave-uniform ch-group
    int xg = x0 + pxl;

    f32x2 a2[9];
    #pragma unroll
    for (int i = 0; i < 9; i++) a2[i] = {0.f, 0.f};

    #pragma unroll 2
    for (int ci = 0; ci < 8; ci++) {
        int cg = g * 8 + ci;
        const float* xpl = x + (size_t)(b * CI + cg) * HWSZ;
        #pragma unroll
        for (int ky = 0; ky < 3; ky++) {
            int yy = y + ky - 1;
            if ((unsigned)yy >= 128u) continue;           // uniform skip
            const float* xr = xpl + yy * WW;
            #pragma unroll
            for (int kx = 0; kx < 3; kx++) {
                int xx = xg + kx - 1;
                float v = ((unsigned)xx < 128u) ? xr[xx] : 0.f;
                const f32x2* wr2 = (const f32x2*)(wP + (cg * 9 + ky * 3 + kx) * 20);
                f32x2 v2 = {v, v};
                #pragma unroll
                for (int j = 0; j < 9; j++)
                    a2[j] = __builtin_elementwise_fma(v2, wr2[j], a2[j]);
            }
        }
    }

    // fused NHWC f16 emit: this thread's 8 channels of center tap (L1-hot)
    {
        const float* xc = x + ((size_t)(b * CI + g * 8) * HH + y) * WW + xg;
        unsigned short c8[8];
        #pragma unroll
        for (int ci = 0; ci < 8; ci++)
            c8[ci] = __half_as_ushort(__float2half_rn(xc[(size_t)ci * HWSZ]));
        size_t pbase = (size_t)((b * HH + y) * WW + xg) * 64 + g * 8;
        *(uint4*)(xT + pbase) = *(const uint4*)&c8[0];
    }

    #pragma unroll
    for (int i = 0; i < 9; i++) sm[t * 9 + i] = a2[i];
    __syncthreads();

    for (int task = t; task < 576; task += 512) {
        int p2 = task & 63, n = task >> 6;
        float ay = b_off[n], ax = b_off[9 + n];
        int jy = n >> 1, cy = n & 1;
        int jx = (9 + n) >> 1, cx = (9 + n) & 1;
        #pragma unroll
        for (int gg = 0; gg < 8; gg++) {
            ay += sm[(gg * 64 + p2) * 9 + jy][cy];
            ax += sm[(gg * 64 + p2) * 9 + jx][cx];
        }
        float py  = (float)(y + (n / 3)) + ay;
        float pxc = (float)(x0 + p2 + (n % 3)) + ax;
        float fy = floorf(py), fx = floorf(pxc);
        if (py  < 1.f || py  > 128.f) py  = fy;       // pad snap
        if (pxc < 1.f || pxc > 128.f) pxc = fx;
        py  = fminf(fmaxf(py,  0.f), 129.f);
        pxc = fminf(fmaxf(pxc, 0.f), 129.f);

        fy = floorf(py); fx = floorf(pxc);
        int y0 = (int)fy, x0i = (int)fx;              // padded coords [0,129]
        int y1 = min(y0 + 1, 129), x1 = min(x0i + 1, 129);
        float wyl = 1.f + (fy - py);
        float wyr = 1.f - ((float)y1 - py);
        float wxl = 1.f + (fx - pxc);
        float wxr = 1.f - ((float)x1 - pxc);
        float glt = wyl * wxl, grb = wyr * wxr, glb = wyl * wxr, grt = wyr * wxl;
        if ((unsigned)(y0  - 1) >= 128u) { glt = 0.f; glb = 0.f; }
        if ((unsigned)(y1  - 1) >= 128u) { grb = 0.f; grt = 0.f; }
        if ((unsigned)(x0i - 1) >= 128u) { glt = 0.f; grt = 0.f; }
        if ((unsigned)(x1  - 1) >= 128u) { grb = 0.f; glb = 0.f; }

        uchar4 cu;
        cu.x = (unsigned char)min(max(y0  - 1, 0), 127);
        cu.y = (unsigned char)min(max(y1  - 1, 0), 127);
        cu.z = (unsigned char)min(max(x0i - 1, 0), 127);
        cu.w = (unsigned char)min(max(x1  - 1, 0), 127);
        ushort4 gu;
        gu.x = __half_as_ushort(__float2half_rn(glt));
        gu.y = __half_as_ushort(__float2half_rn(grb));
        gu.z = __half_as_ushort(__float2half_rn(glb));
        gu.w = __half_as_ushort(__float2half_rn(grt));
        int pixIdx = (b * HH + y) * WW + x0 + p2;
        dC[n * TOTPX + pixIdx] = cu;
        dG[n * TOTPX + pixIdx] = gu;
    }
}

// ---- K2: 2-deep gather pipeline, quad-coalesced, Rd redistribute, W-DMA dbuf ----
// Grid 1024 (4 blk/CU). Block = 64 px x 128 oc, 4 waves; wave = 16 px x 128 oc.
__global__ __launch_bounds__(256, 4) void k_main(
    const unsigned short* __restrict__ xT, const unsigned short* __restrict__ waF,
    const uchar4* __restrict__ dC, const ushort4* __restrict__ dG,
    float* __restrict__ out)
{
    __shared__ __align__(16) unsigned short Wl[2][8192];   // 2 x 16KB W chunks
    __shared__ __align__(16) unsigned short Rd[4][1024];   // per-wave redistribute

    int bid0 = blockIdx.x;                     // 1024 = 8 XCD x 128
    int bid  = ((bid0 & 7) << 7) | (bid0 >> 3);
    int b = bid >> 8, rem = bid & 255, y = rem >> 1, x0 = (rem & 1) << 6;

    int t = threadIdx.x, lane = t & 63, wv = t >> 6;
    int col = lane & 15, koct = lane >> 4;     // MFMA role
    int gp = lane >> 2, gq = lane & 3;         // gather role
    int qo = gq * 8;
    int pixG = (b * HH + y) * WW + x0 + wv * 16 + gp;
    const unsigned short* xb = xT + (size_t)b * (HWSZ * 64);

    half8 raw0[8], raw1[8];                    // 2-deep gather buffers
    f32x4 acc[8];
    #pragma unroll
    for (int i = 0; i < 8; i++) acc[i] = {0.f, 0.f, 0.f, 0.f};

    auto stage = [&](int kc, int buf) {
        #pragma unroll
        for (int p = 0; p < 4; p++) {
            const unsigned short* gsrc = waF + kc * 8192 + wv * 512 + p * 2048 + lane * 8;
            __builtin_amdgcn_global_load_lds(
                (const __attribute__((address_space(1))) unsigned int*)gsrc,
                (__attribute__((address_space(3))) unsigned int*)&Wl[buf][wv * 512 + p * 2048],
                16, 0, 0);
        }
    };
    auto issue = [&](uchar4 cu, half8* raw) {  // quad-coalesced: 1 line per quad
        int o00 = (((int)cu.x * WW) + (int)cu.z) << 6;
        int o11 = (((int)cu.y * WW) + (int)cu.w) << 6;
        int o01 = (((int)cu.x * WW) + (int)cu.w) << 6;
        int o10 = (((int)cu.y * WW) + (int)cu.z) << 6;
        raw[0] = *(const half8*)(xb + o00 + qo);
        raw[1] = *(const half8*)(xb + o11 + qo);
        raw[2] = *(const half8*)(xb + o01 + qo);
        raw[3] = *(const half8*)(xb + o10 + qo);
        raw[4] = *(const half8*)(xb + o00 + qo + 32);
        raw[5] = *(const half8*)(xb + o11 + qo + 32);
        raw[6] = *(const half8*)(xb + o01 + qo + 32);
        raw[7] = *(const half8*)(xb + o10 + qo + 32);
    };
    auto combine_store = [&](const half8* raw, ushort4 gu) {
        __half2 q0 = __half2half2(__ushort_as_half(gu.x));
        __half2 q1 = __half2half2(__ushort_as_half(gu.y));
        __half2 q2 = __half2half2(__ushort_as_half(gu.z));
        __half2 q3 = __half2half2(__ushort_as_half(gu.w));
        #pragma unroll
        for (int ks = 0; ks < 2; ks++) {
            __half2 vm[4];
            #pragma unroll
            for (int m = 0; m < 4; m++) {
                __half2 v = __hmul2(((const __half2*)&raw[ks * 4 + 0])[m], q0);
                v = __hfma2(((const __half2*)&raw[ks * 4 + 1])[m], q1, v);
                v = __hfma2(((const __half2*)&raw[ks * 4 + 2])[m], q2, v);
                v = __hfma2(((const __half2*)&raw[ks * 4 + 3])[m], q3, v);
                vm[m] = v;
            }
            int gz = (4 * ks + gq) ^ (gp & 7);
            *(uint4*)(&Rd[wv][0] + gp * 64 + gz * 8) = *(const uint4*)vm;
        }
    };

    // ---- prologue: W(0); desc(0..2); gathers(0)->raw0, gathers(1)->raw1 ----
    stage(0, 0);
    __builtin_amdgcn_sched_barrier(0);
    uchar4  cuA = dC[pixG];              ushort4 guA = dG[pixG];
    uchar4  cuB = dC[TOTPX + pixG];      ushort4 guB = dG[TOTPX + pixG];
    uchar4  cuC = dC[2 * TOTPX + pixG];  ushort4 guC = dG[2 * TOTPX + pixG];
    __builtin_amdgcn_sched_barrier(0);
    issue(cuA, raw0);
    issue(cuB, raw1);
    __builtin_amdgcn_sched_barrier(0);
    asm volatile("s_waitcnt vmcnt(16)" ::: "memory");  // W(0)+descs done; g0,g1 fly
    __builtin_amdgcn_s_barrier();
    __builtin_amdgcn_sched_barrier(0);

// ITER order: [W(kc+1)] [desc(kc+3)] [combine(kc)] [bfr] [issue g(kc+2) into
// same raw] [MFMA] [vmcnt(10): drains g(kc+1)+W(kc+1), leaves desc+g(kc+2)].
#define ITER(KC)                                                              \
  {                                                                           \
    if ((KC) < 8) stage((KC) + 1, ((KC) & 1) ^ 1);                            \
    __builtin_amdgcn_sched_barrier(0);                                        \
    uchar4 cuN; ushort4 guN;                                                  \
    if ((KC) < 6) { cuN = dC[((KC)+3) * TOTPX + pixG];                        \
                    guN = dG[((KC)+3) * TOTPX + pixG]; }                      \
    __builtin_amdgcn_sched_barrier(0);                                        \
    combine_store(((KC) & 1) ? raw1 : raw0, guA);                             \
    asm volatile("s_waitcnt lgkmcnt(0)" ::: "memory");                        \
    __builtin_amdgcn_sched_barrier(0);                                        \
    half8 bfr[2];                                                             \
    _Pragma("unroll")                                                         \
    for (int ks = 0; ks < 2; ks++) {                                          \
      int gz = (4 * ks + koct) ^ (col & 7);                                   \
      bfr[ks] = *(const half8*)(&Rd[wv][0] + col * 64 + gz * 8);              \
    }                                                                         \
    __builtin_amdgcn_sched_barrier(0);                                        \
    if ((KC) < 7) issue(cuC, ((KC) & 1) ? raw1 : raw0);                       \
    __builtin_amdgcn_sched_barrier(0);                                        \
    __builtin_amdgcn_s_setprio(1);                                            \
    { const unsigned short* wl = &Wl[(KC) & 1][0];                            \
      _Pragma("unroll")                                                       \
      for (int ks = 0; ks < 2; ks++)                                          \
        _Pragma("unroll")                                                     \
        for (int i = 0; i < 8; i++) {                                         \
          half8 af = *(const half8*)(wl + (i * 2 + ks) * 512 + lane * 8);     \
          acc[i] = __builtin_amdgcn_mfma_f32_16x16x32_f16(af, bfr[ks],        \
                                                          acc[i], 0, 0, 0); } } \
    __builtin_amdgcn_s_setprio(0);                                            \
    if ((KC) < 8) {                                                           \
      if ((KC) < 6)      asm volatile("s_waitcnt vmcnt(10)" ::: "memory");    \
      else if ((KC) == 6) asm volatile("s_waitcnt vmcnt(8)" ::: "memory");    \
      else               asm volatile("s_waitcnt vmcnt(0)" ::: "memory");     \
      __builtin_amdgcn_s_barrier();                                           \
      __builtin_amdgcn_sched_barrier(0);                                      \
    }                                                                         \
    cuA = cuB; guA = guB; cuB = cuC; guB = guC;                               \
    if ((KC) < 6) { cuC = cuN; guC = guN; }                                   \
  }

    ITER(0) ITER(1) ITER(2) ITER(3) ITER(4) ITER(5) ITER(6) ITER(7) ITER(8)
#undef ITER

    // epilogue: D row -> oc, col -> px (64B segments)
    int ob0 = b * CO * HWSZ + y * WW + x0 + wv * 16 + col;
    #pragma unroll
    for (int i = 0; i < 8; i++)
        #pragma unroll
        for (int r = 0; r < 4; r++) {
            int oc = i * 16 + koct * 4 + r;
            out[ob0 + oc * HWSZ] = acc[i][r];
        }
}

extern "C" void kernel_launch(void* const* d_in, const int* in_sizes, int n_in,
                              void* d_out, int out_size, void* d_ws, size_t ws_size,
                              hipStream_t stream) {
    const float* x      = (const float*)d_in[0];
    const float* w_off  = (const float*)d_in[1];
    const float* b_off  = (const float*)d_in[2];
    const float* w_conv = (const float*)d_in[3];
    float* out = (float*)d_out;

    // ws: xT 8MB | dC 2.25MB | dG 4.5MB | waF 144KB | wP 46KB
    char* wsb = (char*)d_ws;
    unsigned short* xT  = (unsigned short*)wsb;
    uchar4*         dC  = (uchar4*)(wsb + (size_t)TOTPX * 64 * 2);
    ushort4*        dG  = (ushort4*)(wsb + (size_t)TOTPX * 64 * 2 + (size_t)NN * TOTPX * 4);
    unsigned short* waF = (unsigned short*)(wsb + (size_t)TOTPX * 64 * 2
                                            + (size_t)NN * TOTPX * 4 + (size_t)NN * TOTPX * 8);
    float*          wP  = (float*)(wsb + (size_t)TOTPX * 64 * 2
                                   + (size_t)NN * TOTPX * 4 + (size_t)NN * TOTPX * 8
                                   + (size_t)CO * 576 * 2);

    k_prep_w<<<(CO * 576 + 255) / 256, 256, 0, stream>>>(w_conv, waF, w_off, wP);
    k_offsets<<<1024, 512, 0, stream>>>(x, wP, b_off, dC, dG, xT);
    k_main<<<1024, 256, 0, stream>>>(xT, waF, dC, dG, out);
}

// Round 19
// 54.961 us; speedup vs baseline: 1.1225x; 1.1225x over previous
//
#include <hip/hip_runtime.h>
#include <hip/hip_fp16.h>

#define NB 4
#define CI 64
#define CO 128
#define HH 128
#define WW 128
#define HWSZ (HH*WW)
#define TOTPX (NB*HWSZ)     // 65536
#define NN 9

using half8 = __attribute__((ext_vector_type(8))) _Float16;
using f32x4 = __attribute__((ext_vector_type(4))) float;
using f32x2 = __attribute__((ext_vector_type(2))) float;

// ---- K0: prep W (fragment-major f16) + offset-conv weights (tap-major) ----
__global__ __launch_bounds__(256) void k_prep_w(const float* __restrict__ w,
                                                unsigned short* __restrict__ waF,
                                                const float* __restrict__ w_off,
                                                float* __restrict__ wP) {
    int t = blockIdx.x * 256 + threadIdx.x;
    if (t < CO * 576) {
        int oc = t / 576, r = t - oc * 576;
        int c = r / 9, n = r - c * 9;
        int i = oc >> 4, col = oc & 15;
        int ks = c >> 5, koct = (c >> 3) & 3, e = c & 7;
        int lane = koct * 16 + col;
        waF[(n * 16 + i * 2 + ks) * 512 + lane * 8 + e] =
            __half_as_ushort(__float2half_rn(w[t]));
    }
    if (t < 18 * 576) {
        int oc = t / 576, r = t - oc * 576;
        wP[r * 20 + oc] = w_off[t];
    }
}

// -- K1 v3: full-row blocks, 2 px/thread, aligned float2 taps (positions frozen) --
// 512 thr = 64 pairs x 8 ch-groups (wave-uniform). Grid 512 (b,y).
__global__ __launch_bounds__(512, 4) void k_offsets(
    const float* __restrict__ x, const float* __restrict__ wP,
    const float* __restrict__ b_off, uchar4* __restrict__ dC,
    ushort4* __restrict__ dG, unsigned short* __restrict__ xT)
{
    __shared__ f32x2 sm[4 * 128 * 9];   // 36,864 B (two 4-group reduce passes)
    int bid = blockIdx.x;
    int b = bid >> 7, y = bid & 127;
    int t = threadIdx.x;
    int pr = t & 63;                                    // pixel pair: 2pr, 2pr+1
    int g  = __builtin_amdgcn_readfirstlane(t >> 6);    // wave-uniform ch-group

    f32x2 a0[9], a1[9];
    #pragma unroll
    for (int i = 0; i < 9; i++) { a0[i] = {0.f, 0.f}; a1[i] = {0.f, 0.f}; }
    unsigned short c16a[8], c16b[8];

    #pragma unroll
    for (int ci = 0; ci < 8; ci++) {
        int cg = g * 8 + ci;
        const float* xpl = x + (size_t)(b * CI + cg) * HWSZ;
        #pragma unroll
        for (int ky = 0; ky < 3; ky++) {
            int yy = y + ky - 1;
            if ((unsigned)yy >= 128u) continue;         // uniform skip
            const float* xr = xpl + yy * WW + 2 * pr;
            int offL = (pr > 0)  ? -2 : 0;              // stay in-buffer
            int offR = (pr < 63) ?  2 : 0;
            f32x2 v0 = *(const f32x2*)(xr);
            f32x2 vl = *(const f32x2*)(xr + offL);
            f32x2 vr = *(const f32x2*)(xr + offR);
            if (pr == 0)  vl = (f32x2){0.f, 0.f};       // cols -2,-1 -> 0
            if (pr == 63) vr = (f32x2){0.f, 0.f};       // cols 128,129 -> 0
            if (ky == 1) {                              // center taps for xT emit
                c16a[ci] = __half_as_ushort(__float2half_rn(v0[0]));
                c16b[ci] = __half_as_ushort(__float2half_rn(v0[1]));
            }
            #pragma unroll
            for (int kx = 0; kx < 3; kx++) {
                float ta = (kx == 0) ? vl[1] : (kx == 1) ? v0[0] : v0[1];  // px0
                float tb = (kx == 0) ? v0[0] : (kx == 1) ? v0[1] : vr[0];  // px1
                const f32x2* wr2 = (const f32x2*)(wP + (cg * 9 + ky * 3 + kx) * 20);
                f32x2 va = {ta, ta}, vb = {tb, tb};
                #pragma unroll
                for (int j = 0; j < 9; j++) {
                    a0[j] = __builtin_elementwise_fma(va, wr2[j], a0[j]);
                    a1[j] = __builtin_elementwise_fma(vb, wr2[j], a1[j]);
                }
            }
        }
    }

    // NHWC f16 emit: 2 pixels x 8 channels
    {
        size_t p0 = (size_t)((b * HH + y) * WW + 2 * pr) * 64 + g * 8;
        *(uint4*)(xT + p0)      = *(const uint4*)&c16a[0];
        *(uint4*)(xT + p0 + 64) = *(const uint4*)&c16b[0];
    }

    // ---- reduce pass A: groups 0..3 ----
    if (g < 4) {
        int base0 = (g * 128 + 2 * pr) * 9;
        #pragma unroll
        for (int j = 0; j < 9; j++) { sm[base0 + j] = a0[j]; sm[base0 + 9 + j] = a1[j]; }
    }
    __syncthreads();
    float ay[3], ax[3];
    #pragma unroll
    for (int it = 0; it < 3; it++) {
        int task = t + it * 512;
        if (task < 1152) {
            int p2 = task & 127, n = task >> 7;
            float sy = b_off[n], sx = b_off[9 + n];
            int jy = n >> 1, cy = n & 1;
            int jx = (9 + n) >> 1, cx = (9 + n) & 1;
            #pragma unroll
            for (int gg = 0; gg < 4; gg++) {
                sy += sm[(gg * 128 + p2) * 9 + jy][cy];
                sx += sm[(gg * 128 + p2) * 9 + jx][cx];
            }
            ay[it] = sy; ax[it] = sx;
        } else { ay[it] = 0.f; ax[it] = 0.f; }
    }
    __syncthreads();
    // ---- reduce pass B: groups 4..7 ----
    if (g >= 4) {
        int base0 = ((g - 4) * 128 + 2 * pr) * 9;
        #pragma unroll
        for (int j = 0; j < 9; j++) { sm[base0 + j] = a0[j]; sm[base0 + 9 + j] = a1[j]; }
    }
    __syncthreads();
    #pragma unroll
    for (int it = 0; it < 3; it++) {
        int task = t + it * 512;
        if (task < 1152) {
            int p2 = task & 127, n = task >> 7;
            float sy = ay[it], sx = ax[it];
            int jy = n >> 1, cy = n & 1;
            int jx = (9 + n) >> 1, cx = (9 + n) & 1;
            #pragma unroll
            for (int gg = 0; gg < 4; gg++) {
                sy += sm[(gg * 128 + p2) * 9 + jy][cy];
                sx += sm[(gg * 128 + p2) * 9 + jx][cx];
            }
            float py  = (float)(y + (n / 3)) + sy;
            float pxc = (float)(p2 + (n % 3)) + sx;
            float fy = floorf(py), fx = floorf(pxc);
            if (py  < 1.f || py  > 128.f) py  = fy;     // pad snap
            if (pxc < 1.f || pxc > 128.f) pxc = fx;
            py  = fminf(fmaxf(py,  0.f), 129.f);
            pxc = fminf(fmaxf(pxc, 0.f), 129.f);

            fy = floorf(py); fx = floorf(pxc);
            int y0 = (int)fy, x0i = (int)fx;            // padded coords [0,129]
            int y1 = min(y0 + 1, 129), x1 = min(x0i + 1, 129);
            float wyl = 1.f + (fy - py);
            float wyr = 1.f - ((float)y1 - py);
            float wxl = 1.f + (fx - pxc);
            float wxr = 1.f - ((float)x1 - pxc);
            float glt = wyl * wxl, grb = wyr * wxr, glb = wyl * wxr, grt = wyr * wxl;
            if ((unsigned)(y0  - 1) >= 128u) { glt = 0.f; glb = 0.f; }
            if ((unsigned)(y1  - 1) >= 128u) { grb = 0.f; grt = 0.f; }
            if ((unsigned)(x0i - 1) >= 128u) { glt = 0.f; grt = 0.f; }
            if ((unsigned)(x1  - 1) >= 128u) { grb = 0.f; glb = 0.f; }

            uchar4 cu;
            cu.x = (unsigned char)min(max(y0  - 1, 0), 127);
            cu.y = (unsigned char)min(max(y1  - 1, 0), 127);
            cu.z = (unsigned char)min(max(x0i - 1, 0), 127);
            cu.w = (unsigned char)min(max(x1  - 1, 0), 127);
            ushort4 gu;
            gu.x = __half_as_ushort(__float2half_rn(glt));
            gu.y = __half_as_ushort(__float2half_rn(grb));
            gu.z = __half_as_ushort(__float2half_rn(glb));
            gu.w = __half_as_ushort(__float2half_rn(grt));
            int pixIdx = (b * HH + y) * WW + p2;
            dC[n * TOTPX + pixIdx] = cu;
            dG[n * TOTPX + pixIdx] = gu;
        }
    }
}

// ------- K2: quad-coalesced gather -> per-wave LDS redistribute -> MFMA -------
// r12 version verbatim (grid 512, 32px/wave dual-group, af reused x2).
__global__ __launch_bounds__(256, 2) void k_main(
    const unsigned short* __restrict__ xT, const unsigned short* __restrict__ waF,
    const uchar4* __restrict__ dC, const ushort4* __restrict__ dG,
    float* __restrict__ out)
{
    __shared__ __align__(16) unsigned short Wl[2][8192];      // 2 x 16KB W chunks
    __shared__ __align__(16) unsigned short Rd[4][2][1024];   // per-wave redistribute

    int bid0 = blockIdx.x;                     // 512 = 8 XCD x 64
    int bid  = ((bid0 & 7) << 6) | (bid0 >> 3);
    int b = bid >> 7, y = bid & 127;

    int t = threadIdx.x, lane = t & 63, wv = t >> 6;
    int col = lane & 15, koct = lane >> 4;     // MFMA role
    int gp = lane >> 2, gq = lane & 3;         // gather role
    int qo = gq * 8;
    int rowbase = (b * HH + y) * WW;
    int pixG0 = rowbase + wv * 32 + gp;
    int pixG1 = pixG0 + 16;
    const unsigned short* xb = xT + (size_t)b * (HWSZ * 64);

    half8 raw0[8], raw1[8];
    f32x4 acc0[8], acc1[8];
    #pragma unroll
    for (int i = 0; i < 8; i++) { acc0[i] = {0.f,0.f,0.f,0.f}; acc1[i] = {0.f,0.f,0.f,0.f}; }

    auto stage = [&](int kc, int buf) {
        #pragma unroll
        for (int p = 0; p < 4; p++) {
            const unsigned short* gsrc = waF + kc * 8192 + wv * 512 + p * 2048 + lane * 8;
            __builtin_amdgcn_global_load_lds(
                (const __attribute__((address_space(1))) unsigned int*)gsrc,
                (__attribute__((address_space(3))) unsigned int*)&Wl[buf][wv * 512 + p * 2048],
                16, 0, 0);
        }
    };
    auto issue = [&](uchar4 cu, half8* raw) {
        int o00 = (((int)cu.x * WW) + (int)cu.z) << 6;
        int o11 = (((int)cu.y * WW) + (int)cu.w) << 6;
        int o01 = (((int)cu.x * WW) + (int)cu.w) << 6;
        int o10 = (((int)cu.y * WW) + (int)cu.z) << 6;
        raw[0] = *(const half8*)(xb + o00 + qo);
        raw[1] = *(const half8*)(xb + o11 + qo);
        raw[2] = *(const half8*)(xb + o01 + qo);
        raw[3] = *(const half8*)(xb + o10 + qo);
        raw[4] = *(const half8*)(xb + o00 + qo + 32);
        raw[5] = *(const half8*)(xb + o11 + qo + 32);
        raw[6] = *(const half8*)(xb + o01 + qo + 32);
        raw[7] = *(const half8*)(xb + o10 + qo + 32);
    };
    auto combine_store = [&](const half8* raw, ushort4 gu, unsigned short* rbase) {
        __half2 q0 = __half2half2(__ushort_as_half(gu.x));
        __half2 q1 = __half2half2(__ushort_as_half(gu.y));
        __half2 q2 = __half2half2(__ushort_as_half(gu.z));
        __half2 q3 = __half2half2(__ushort_as_half(gu.w));
        #pragma unroll
        for (int ks = 0; ks < 2; ks++) {
            __half2 vm[4];
            #pragma unroll
            for (int m = 0; m < 4; m++) {
                __half2 v = __hmul2(((const __half2*)&raw[ks * 4 + 0])[m], q0);
                v = __hfma2(((const __half2*)&raw[ks * 4 + 1])[m], q1, v);
                v = __hfma2(((const __half2*)&raw[ks * 4 + 2])[m], q2, v);
                v = __hfma2(((const __half2*)&raw[ks * 4 + 3])[m], q3, v);
                vm[m] = v;
            }
            int gz = (4 * ks + gq) ^ (gp & 7);
            *(uint4*)(rbase + gp * 64 + gz * 8) = *(const uint4*)vm;
        }
    };

    stage(0, 0);
    __builtin_amdgcn_sched_barrier(0);
    uchar4 cuA0 = dC[pixG0],         cuA1 = dC[pixG1];
    ushort4 guA0 = dG[pixG0],        guA1 = dG[pixG1];
    uchar4 cuB0 = dC[TOTPX + pixG0], cuB1 = dC[TOTPX + pixG1];
    ushort4 guB0 = dG[TOTPX + pixG0], guB1 = dG[TOTPX + pixG1];
    __builtin_amdgcn_sched_barrier(0);
    issue(cuA0, raw0);
    issue(cuA1, raw1);
    __builtin_amdgcn_sched_barrier(0);
    asm volatile("s_waitcnt vmcnt(16)" ::: "memory");
    __builtin_amdgcn_s_barrier();
    __builtin_amdgcn_sched_barrier(0);

#define ITER(KC)                                                              \
  {                                                                           \
    if ((KC) < 8) stage((KC) + 1, ((KC) & 1) ^ 1);                            \
    __builtin_amdgcn_sched_barrier(0);                                        \
    uchar4 cuN0, cuN1; ushort4 guN0, guN1;                                    \
    if ((KC) < 7) {                                                           \
      cuN0 = dC[((KC)+2) * TOTPX + pixG0]; guN0 = dG[((KC)+2) * TOTPX + pixG0]; \
      cuN1 = dC[((KC)+2) * TOTPX + pixG1]; guN1 = dG[((KC)+2) * TOTPX + pixG1]; \
    }                                                                         \
    __builtin_amdgcn_sched_barrier(0);                                        \
    combine_store(raw0, guA0, &Rd[wv][0][0]);                                 \
    combine_store(raw1, guA1, &Rd[wv][1][0]);                                 \
    asm volatile("s_waitcnt lgkmcnt(0)" ::: "memory");                        \
    __builtin_amdgcn_sched_barrier(0);                                        \
    half8 bfr0[2], bfr1[2];                                                   \
    _Pragma("unroll")                                                         \
    for (int ks = 0; ks < 2; ks++) {                                          \
      int gz = (4 * ks + koct) ^ (col & 7);                                   \
      bfr0[ks] = *(const half8*)(&Rd[wv][0][0] + col * 64 + gz * 8);          \
      bfr1[ks] = *(const half8*)(&Rd[wv][1][0] + col * 64 + gz * 8);          \
    }                                                                         \
    __builtin_amdgcn_sched_barrier(0);                                        \
    if ((KC) < 8) { issue(cuB0, raw0); issue(cuB1, raw1); }                   \
    __builtin_amdgcn_sched_barrier(0);                                        \
    __builtin_amdgcn_s_setprio(1);                                            \
    { const unsigned short* wl = &Wl[(KC) & 1][0];                            \
      _Pragma("unroll")                                                       \
      for (int ks = 0; ks < 2; ks++)                                          \
        _Pragma("unroll")                                                     \
        for (int i = 0; i < 8; i++) {                                         \
          half8 af = *(const half8*)(wl + (i * 2 + ks) * 512 + lane * 8);     \
          acc0[i] = __builtin_amdgcn_mfma_f32_16x16x32_f16(af, bfr0[ks],      \
                                                           acc0[i], 0, 0, 0); \
          acc1[i] = __builtin_amdgcn_mfma_f32_16x16x32_f16(af, bfr1[ks],      \
                                                           acc1[i], 0, 0, 0); \
        } }                                                                   \
    __builtin_amdgcn_s_setprio(0);                                            \
    if ((KC) < 8) {                                                           \
      if ((KC) < 7) asm volatile("s_waitcnt vmcnt(20)" ::: "memory");         \
      else          asm volatile("s_waitcnt vmcnt(16)" ::: "memory");         \
      __builtin_amdgcn_s_barrier();                                           \
      __builtin_amdgcn_sched_barrier(0);                                      \
    }                                                                         \
    guA0 = guB0; guA1 = guB1;                                                 \
    cuB0 = ((KC) < 7) ? cuN0 : cuB0; guB0 = ((KC) < 7) ? guN0 : guB0;         \
    cuB1 = ((KC) < 7) ? cuN1 : cuB1; guB1 = ((KC) < 7) ? guN1 : guB1;         \
  }

    ITER(0) ITER(1) ITER(2) ITER(3) ITER(4) ITER(5) ITER(6) ITER(7) ITER(8)
#undef ITER

    int ob0 = b * CO * HWSZ + y * WW + wv * 32 + col;
    #pragma unroll
    for (int i = 0; i < 8; i++)
        #pragma unroll
        for (int r = 0; r < 4; r++) {
            int oc = i * 16 + koct * 4 + r;
            out[ob0 + oc * HWSZ]      = acc0[i][r];
            out[ob0 + oc * HWSZ + 16] = acc1[i][r];
        }
}

extern "C" void kernel_launch(void* const* d_in, const int* in_sizes, int n_in,
                              void* d_out, int out_size, void* d_ws, size_t ws_size,
                              hipStream_t stream) {
    const float* x      = (const float*)d_in[0];
    const float* w_off  = (const float*)d_in[1];
    const float* b_off  = (const float*)d_in[2];
    const float* w_conv = (const float*)d_in[3];
    float* out = (float*)d_out;

    // ws: xT 8MB | dC 2.25MB | dG 4.5MB | waF 144KB | wP 46KB
    char* wsb = (char*)d_ws;
    unsigned short* xT  = (unsigned short*)wsb;
    uchar4*         dC  = (uchar4*)(wsb + (size_t)TOTPX * 64 * 2);
    ushort4*        dG  = (ushort4*)(wsb + (size_t)TOTPX * 64 * 2 + (size_t)NN * TOTPX * 4);
    unsigned short* waF = (unsigned short*)(wsb + (size_t)TOTPX * 64 * 2
                                            + (size_t)NN * TOTPX * 4 + (size_t)NN * TOTPX * 8);
    float*          wP  = (float*)(wsb + (size_t)TOTPX * 64 * 2
                                   + (size_t)NN * TOTPX * 4 + (size_t)NN * TOTPX * 8
                                   + (size_t)CO * 576 * 2);

    k_prep_w<<<(CO * 576 + 255) / 256, 256, 0, stream>>>(w_conv, waF, w_off, wP);
    k_offsets<<<512, 512, 0, stream>>>(x, wP, b_off, dC, dG, xT);
    k_main<<<512, 256, 0, stream>>>(xT, waF, dC, dG, out);
}